// Round 2
// baseline (2403.974 us; speedup 1.0000x reference)
//
#include <hip/hip_runtime.h>
#include <hip/hip_bf16.h>
#include <cstdint>

#define B_   2048
#define H_   512
#define T_   128
#define V_   64
#define FOURH 2048

typedef __bf16 bf16x8 __attribute__((ext_vector_type(8)));
typedef float  floatx4 __attribute__((ext_vector_type(4)));
typedef int    intx4   __attribute__((ext_vector_type(4)));

__device__ __forceinline__ unsigned short f2bf(float f) {
    union { float f; uint32_t u; } v; v.f = f;
    uint32_t r = v.u + 0x7fff + ((v.u >> 16) & 1);
    return (unsigned short)(r >> 16);
}

// v_rcp_f32 (~1 ulp, rel err ~1e-7 << bf16's 2^-8). Avoids the ~11-op exact
// division sequence the compiler emits without fast-math.
__device__ __forceinline__ float rcp_(float x) {
    float r; asm("v_rcp_f32 %0, %1" : "=v"(r) : "v"(x)); return r;
}
__device__ __forceinline__ float sigmoidf_(float x) {
    return rcp_(1.0f + __expf(-x));   // exp(-inf)->inf -> rcp -> 0 : safe
}
__device__ __forceinline__ float tanhf_(float x) {
    float e = __expf(fminf(-2.0f * x, 80.0f));
    return (1.0f - e) * rcp_(1.0f + e);
}

__device__ __forceinline__ void global_to_lds16(const unsigned short* g, unsigned short* l) {
    __builtin_amdgcn_global_load_lds(
        (const __attribute__((address_space(1))) unsigned int*)g,
        (__attribute__((address_space(3))) unsigned int*)l, 16, 0, 0);
}

// System-coherent 16B load (bypass L1+L2, read MALL — cross-XCD safe), blocking.
__device__ __forceinline__ bf16x8 load16_sys(const unsigned short* p) {
    bf16x8 d;
    asm volatile("global_load_dwordx4 %0, %1, off sc0 sc1\n\t"
                 "s_waitcnt vmcnt(0)"
                 : "=v"(d) : "v"(p));
    return d;
}

// ---------------------------------------------------------------------------
// Flag-based sync: producer j of group bi posts flag[bi*64+j] = t+1 via
// sc0/sc1 store (after its h stores drained to the MALL). Consumers poll
// READ-ONLY with sc0/sc1 loads (must bypass caches — a cached poll line would
// never update). h DATA, by contrast, is read with PLAIN cached loads guarded
// by one agent-acquire fence (buffer_inv) per step — see lstm_persistent.
// ---------------------------------------------------------------------------
__device__ __forceinline__ void flag_prefetch(const unsigned int* fp, intx4& f) {
    asm volatile("global_load_dwordx4 %0, %1, off sc0 sc1"
                 : "=v"(f) : "v"(fp) : "memory");
}
__device__ __forceinline__ bool flag_ok(const intx4& f, unsigned int tgt) {
    return (unsigned int)f[0] >= tgt && (unsigned int)f[1] >= tgt &&
           (unsigned int)f[2] >= tgt && (unsigned int)f[3] >= tgt;
}
__device__ __forceinline__ void wait4(const unsigned int* fp, unsigned int tgt) {
    for (;;) {
        intx4 f;
        asm volatile("global_load_dwordx4 %0, %1, off sc0 sc1\n\t"
                     "s_waitcnt vmcnt(0)"
                     : "=v"(f) : "v"(fp) : "memory");
        if (flag_ok(f, tgt)) return;
        __builtin_amdgcn_s_sleep(1);
    }
}
__device__ __forceinline__ void flag_post(unsigned int* p, unsigned int v) {
    asm volatile("global_store_dword %0, %1, off sc0 sc1" :: "v"(p), "v"(v) : "memory");
}

// ---------------------------------------------------------------------------
// prep: permuted bf16 weights, bf16 z / fc_w, fused permuted bias, zero flags.
// Tile-col layout (per j, 128 cols): c = 64*wn + 16*gate + ln,
// maps to original gate row p = gate*512 + j*32 + (wn*16 + ln).
// ---------------------------------------------------------------------------
__global__ void prep_kernel(const float* __restrict__ z,
                            const float* __restrict__ w_ih,
                            const float* __restrict__ w_hh,
                            const float* __restrict__ b_ih,
                            const float* __restrict__ b_hh,
                            const float* __restrict__ fc_w,
                            unsigned short* __restrict__ Bp_ih,
                            unsigned short* __restrict__ Bp_hh,
                            unsigned short* __restrict__ z_bf,
                            unsigned short* __restrict__ fcw_bf,
                            float* __restrict__ biasp,
                            unsigned int* __restrict__ cnt) {
    int i = blockIdx.x * blockDim.x + threadIdx.x;   // 2048*512 threads
    int col = i >> 9, k = i & 511;
    int jj = col >> 7, cc = col & 127;
    int gate = (cc >> 4) & 3;
    int hcl = ((cc >> 6) << 4) | (cc & 15);
    int p = gate * 512 + jj * 32 + hcl;
    Bp_hh[i] = f2bf(w_hh[p * 512 + k]);
    Bp_ih[i] = f2bf(w_ih[p * 512 + k]);
    z_bf[i]  = f2bf(z[i]);
    if (i < V_ * H_) fcw_bf[i] = f2bf(fc_w[i]);
    if (i < FOURH) {
        int j2 = i >> 7, c2 = i & 127;
        int g2 = (c2 >> 4) & 3;
        int h2 = ((c2 >> 6) << 4) | (c2 & 15);
        int p2 = g2 * 512 + j2 * 32 + h2;
        biasp[i] = b_ih[p2] + b_hh[p2];
    }
    // per-producer flags: 16 groups x 64 uints (256B stride); zero all
    if (i < 1024) cnt[i] = 0;
}

// ---------------------------------------------------------------------------
// Round-1-proven 128x128 (K=512, BK=64) tile core for the x-gates GEMM.
// ---------------------------------------------------------------------------
__device__ __forceinline__ void gemm_tile_r1(
        const unsigned short* __restrict__ Aglob,
        const unsigned short* __restrict__ Bglob,
        int arow0, int brow0,
        unsigned short* As, unsigned short* Bs,
        floatx4 acc[2][8], int w, int l) {
    const int lr = l >> 3;
    const int gl = (l & 7) ^ lr;
    const int ln = l & 15, lq = l >> 4, ls = l & 7;
    for (int kc = 0; kc < 8; ++kc) {
        const int kof = kc * 64 + gl * 8;
        #pragma unroll
        for (int q = 0; q < 4; ++q) {
            const int r0 = (w * 4 + q) * 8;
            global_to_lds16(Aglob + (size_t)(arow0 + r0 + lr) * 512 + kof, As + r0 * 64);
            global_to_lds16(Bglob + (size_t)(brow0 + r0 + lr) * 512 + kof, Bs + r0 * 64);
        }
        __syncthreads();
        #pragma unroll
        for (int kk = 0; kk < 2; ++kk) {
            bf16x8 a[2], b[8];
            #pragma unroll
            for (int mt = 0; mt < 2; ++mt) {
                const int m = 32 * w + 16 * mt + ln;
                const int g = kk * 4 + lq;
                a[mt] = *(const bf16x8*)(As + m * 64 + ((g ^ ls) * 8));
            }
            #pragma unroll
            for (int nt = 0; nt < 8; ++nt) {
                const int n = 16 * nt + ln;
                const int g = kk * 4 + lq;
                b[nt] = *(const bf16x8*)(Bs + n * 64 + ((g ^ ls) * 8));
            }
            #pragma unroll
            for (int mt = 0; mt < 2; ++mt)
                #pragma unroll
                for (int nt = 0; nt < 8; ++nt)
                    acc[mt][nt] = __builtin_amdgcn_mfma_f32_16x16x32_bf16(
                        a[mt], b[nt], acc[mt][nt], 0, 0, 0);
        }
        __syncthreads();
    }
}

__global__ void __launch_bounds__(256) xg_gemm_kernel(
        const unsigned short* __restrict__ z_bf,
        const unsigned short* __restrict__ Bp_ih,
        const float* __restrict__ biasp,
        float* __restrict__ xg) {
    __shared__ unsigned short As[128 * 64];
    __shared__ unsigned short Bs[128 * 64];
    const int bi = blockIdx.x, j = blockIdx.y;
    const int tid = threadIdx.x, w = tid >> 6, l = tid & 63;
    floatx4 acc[2][8];
    const floatx4 zf = {0.f, 0.f, 0.f, 0.f};
    for (int a1 = 0; a1 < 2; ++a1) for (int a2 = 0; a2 < 8; ++a2) acc[a1][a2] = zf;

    gemm_tile_r1(z_bf, Bp_ih, bi * 128, j * 128, As, Bs, acc, w, l);

    const int ln = l & 15, lq = l >> 4;
    #pragma unroll
    for (int mt = 0; mt < 2; ++mt)
        #pragma unroll
        for (int nt = 0; nt < 8; ++nt) {
            const int colp = j * 128 + nt * 16 + ln;
            const float bv = biasp[colp];
            #pragma unroll
            for (int r = 0; r < 4; ++r) {
                const int b = bi * 128 + 32 * w + 16 * mt + lq * 4 + r;
                xg[(size_t)b * FOURH + colp] = acc[mt][nt][r] + bv;
            }
        }
}

// ---------------------------------------------------------------------------
// A staging: issue 4 PLAIN (L1/L2-cached) 16B loads into VGPRs, no wait.
// Correctness vs producers' sc0/sc1 MALL stores is restored by the per-step
// agent-acquire fence (buffer_inv) that precedes the first h read of a step:
// every line read is fetched post-inv from the MALL, and flag gating
// guarantees the MALL already holds step-t data for that chunk. The 16 WGs
// of a group share the stripe through L2 instead of 16x re-reading the MALL.
// LDS sub-layout per kc (8192 ushorts): row r, slot s holds granule s^(r&7).
// ---------------------------------------------------------------------------
__device__ __forceinline__ void stage_issue(const unsigned short* __restrict__ Aglob,
                                            int arow0, int kc, int w, int l,
                                            intx4& t0, intx4& t1, intx4& t2, intx4& t3) {
    const int lr = l >> 3;
    const int gl = (l & 7) ^ lr;
    const int kof = kc * 64 + gl * 8;
    const unsigned short* p0 = Aglob + (size_t)(arow0 + (w * 4 + 0) * 8 + lr) * 512 + kof;
    const unsigned short* p1 = Aglob + (size_t)(arow0 + (w * 4 + 1) * 8 + lr) * 512 + kof;
    const unsigned short* p2 = Aglob + (size_t)(arow0 + (w * 4 + 2) * 8 + lr) * 512 + kof;
    const unsigned short* p3 = Aglob + (size_t)(arow0 + (w * 4 + 3) * 8 + lr) * 512 + kof;
    asm volatile(
        "global_load_dwordx4 %0, %4, off\n\t"
        "global_load_dwordx4 %1, %5, off\n\t"
        "global_load_dwordx4 %2, %6, off\n\t"
        "global_load_dwordx4 %3, %7, off"
        : "=&v"(t0), "=&v"(t1), "=&v"(t2), "=&v"(t3)
        : "v"(p0), "v"(p1), "v"(p2), "v"(p3)
        : "memory");
}

// Commit a 32 KB chunk (2 kc sub-chunks, 8 regs) after a manual vmcnt wait.
__device__ __forceinline__ void commit8(unsigned short* buf, int w, int l,
                                        const intx4* u) {
    asm volatile("s_waitcnt vmcnt(0)" ::: "memory");
    const int lr = l >> 3, sl = (l & 7) * 8;
    #pragma unroll
    for (int kcL = 0; kcL < 2; ++kcL)
        #pragma unroll
        for (int q = 0; q < 4; ++q)
            *(intx4*)(buf + kcL * 8192 + ((w * 4 + q) * 8 + lr) * 64 + sl) = u[kcL * 4 + q];
}

// ---------------------------------------------------------------------------
// Persistent LSTM. Plain launch, 256 WGs (all co-resident by capacity).
// WG=(bi,j); sync via per-producer flags (read-only sc0/sc1 polls).
// h producer side: sc0/sc1 write-through stores -> MALL, drain, flag post.
// h consumer side: ONE agent-acquire fence per step (s_waitcnt + buffer_inv,
// compiler-lowered, placement-agnostic), then PLAIN cached loads — group
// members share the stripe via L2 (16x less MALL read traffic, L2-latency
// staging for all but the first toucher of each line).
// K-loop: 4 chunks x 32 KB, double-buffered, loads for chunk g+1 in flight
// across chunk g's MFMA block.
// ---------------------------------------------------------------------------
__global__ void __launch_bounds__(256, 1) lstm_persistent(
        const unsigned short* __restrict__ Bp_hh,
        const unsigned short* __restrict__ fcw_bf,
        const float* __restrict__ xg,
        const float* __restrict__ fc_b,
        unsigned short* __restrict__ h0b,
        unsigned short* __restrict__ h1b,
        unsigned int* __restrict__ cnt,
        float* __restrict__ out) {
    __shared__ unsigned short AsB0[2 * 8192];  // 32 KiB chunk buf 0 (first 8 KB doubles as hlds)
    __shared__ unsigned short AsB1[2 * 8192];  // 32 KiB chunk buf 1

    const int bx = blockIdx.x;
    const int bi = bx & 15;        // bx%8 == bi%8 for all j -> group L2 locality (perf only)
    const int j  = bx >> 4;
    const int tid = threadIdx.x;
    const int w = tid >> 6, l = tid & 63;
    const int wm = w >> 1, wn = w & 1;
    const int ln = l & 15, lq = l >> 4;
    const bool jlt8 = (j < 8);
    const int j16 = j * 16;
    const int v = 16 * w + ln;
    const float fcb_v = fc_b[v];
    const int arow0 = bi * 128;
    unsigned int* flagp = cnt + bi * 64;       // 256B-padded per-group flag block
    const floatx4 zf = {0.f, 0.f, 0.f, 0.f};

    // ---- recurrent-weight fragments in registers (persistent) ----
    // bq[s][nt]: B row n = j*128 + 64*wn + 16*nt + ln, k = 32*s + 8*lq .. +8
    bf16x8 bq[16][4];
    {
        const unsigned short* bbase =
            Bp_hh + ((size_t)(j * 128 + 64 * wn + ln)) * 512 + lq * 8;
        #pragma unroll
        for (int s = 0; s < 16; ++s)
            #pragma unroll
            for (int nt = 0; nt < 4; ++nt)
                bq[s][nt] = *(const bf16x8*)(bbase + (size_t)nt * 16 * 512 + s * 32);
    }

    // ---- x-gate tile into registers ----
    floatx4 xga[4][4];
    #pragma unroll
    for (int mt = 0; mt < 4; ++mt)
        #pragma unroll
        for (int nt = 0; nt < 4; ++nt)
            #pragma unroll
            for (int r = 0; r < 4; ++r) {
                const int b = arow0 + 64 * wm + 16 * mt + lq * 4 + r;
                xga[mt][nt][r] = xg[(size_t)b * FOURH + j * 128 + 64 * wn + 16 * nt + ln];
            }

    // h transpose buffer: overlays AsB0 (dead at epilogue time)
    unsigned short* hlds = AsB0;               // 128 rows x 32 cols ushort = 8 KB

    // ---- t = 0: c0 = 0 -> c = i*g, h = o*tanh(c) ----
    float cst[4][4];
    #pragma unroll
    for (int mt = 0; mt < 4; ++mt)
        #pragma unroll
        for (int r = 0; r < 4; ++r) {
            float iv = sigmoidf_(xga[mt][0][r]);
            float gv = tanhf_  (xga[mt][2][r]);
            float ov = sigmoidf_(xga[mt][3][r]);
            float cv = iv * gv;
            cst[mt][r] = cv;
            hlds[(64 * wm + 16 * mt + lq * 4 + r) * 32 + (wn * 16 + ln)] = f2bf(ov * tanhf_(cv));
        }
    __syncthreads();
    for (int c = tid; c < 512; c += 256) {      // 512 x 16B coherent stores
        const int row = c >> 2, seg = c & 3;
        intx4 d = *(const intx4*)(hlds + row * 32 + seg * 8);
        const unsigned short* p = h0b + (size_t)(arow0 + row) * 512 + j * 32 + seg * 8;
        asm volatile("global_store_dwordx4 %0, %1, off sc0 sc1" :: "v"(p), "v"(d) : "memory");
    }
    asm volatile("s_waitcnt vmcnt(0)" ::: "memory");
    __syncthreads();
    if (tid == 0) flag_post(flagp + j, 1u);
    intx4 fpre;
    flag_prefetch(flagp, fpre);                // chunk-0 flags for t=1

    unsigned short* hb[2] = {h0b, h1b};
    #pragma unroll 1
    for (int t = 1; t < T_; ++t) {
        const unsigned int tg = (unsigned int)t;

        // chunk-0 readiness: register fast path, poll fallback
        asm volatile("s_waitcnt vmcnt(0)" ::: "memory");
        __builtin_amdgcn_sched_barrier(0);
        if (!flag_ok(fpre, tg)) wait4(flagp, tg);

        // one agent-acquire per step: invalidate L1+L2 so all PLAIN h loads
        // below fetch fresh MALL data (producers store via sc0/sc1 bypass)
        __builtin_amdgcn_fence(__ATOMIC_ACQUIRE, "agent");

        const unsigned short* hprev = hb[(t - 1) & 1];
        unsigned short* hnext = hb[t & 1];

        floatx4 acc[4][4];
        #pragma unroll
        for (int a1 = 0; a1 < 4; ++a1)
            #pragma unroll
            for (int a2 = 0; a2 < 4; ++a2) acc[a1][a2] = zf;
        floatx4 pacc = zf;

        // ---- chunk 0 (kc 0,1): only exposed staging latency of the step ----
        intx4 u[8];
        stage_issue(hprev, arow0, 0, w, l, u[0], u[1], u[2], u[3]);
        stage_issue(hprev, arow0, 1, w, l, u[4], u[5], u[6], u[7]);
        flag_prefetch(flagp + 4, fpre);        // chunk-1 producers (drained by commit8)
        commit8(AsB0, w, l, u);
        __syncthreads();

        #pragma unroll
        for (int g = 0; g < 4; ++g) {
            if (g < 3) {   // loads for chunk g+1 fly across this chunk's MFMA
                __builtin_amdgcn_sched_barrier(0);
                if (!flag_ok(fpre, tg)) wait4(flagp + 4 * (g + 1), tg);
                stage_issue(hprev, arow0, 2 * g + 2, w, l, u[0], u[1], u[2], u[3]);
                stage_issue(hprev, arow0, 2 * g + 3, w, l, u[4], u[5], u[6], u[7]);
                if (g < 2) flag_prefetch(flagp + 4 * (g + 2), fpre);
            }
            const unsigned short* buf = (g & 1) ? AsB1 : AsB0;
            #pragma unroll
            for (int ss = 0; ss < 4; ++ss) {
                const int s = g * 4 + ss;
                const int ga = (ss & 1) * 4 + lq;
                const unsigned short* Ac = buf + (ss >> 1) * 8192;
                bf16x8 af[4];
                #pragma unroll
                for (int mt = 0; mt < 4; ++mt) {
                    const int m = 64 * wm + 16 * mt + ln;
                    af[mt] = *(const bf16x8*)(Ac + m * 64 + ((ga ^ (ln & 7)) * 8));
                }
                #pragma unroll
                for (int mt = 0; mt < 4; ++mt)
                    #pragma unroll
                    for (int nt = 0; nt < 4; ++nt)
                        acc[mt][nt] = __builtin_amdgcn_mfma_f32_16x16x32_bf16(
                            af[mt], bq[s][nt], acc[mt][nt], 0, 0, 0);
                if (jlt8) {
                    bf16x8 ap = *(const bf16x8*)(Ac + (j16 + ln) * 64 + ((ga ^ (ln & 7)) * 8));
                    bf16x8 bp = *(const bf16x8*)(fcw_bf + (size_t)v * 512 + s * 32 + lq * 8);
                    pacc = __builtin_amdgcn_mfma_f32_16x16x32_bf16(ap, bp, pacc, 0, 0, 0);
                }
            }
            if (g < 3) {
                commit8((g & 1) ? AsB0 : AsB1, w, l, u);
                __syncthreads();
            }
        }

        // cell update -> h values into LDS transpose buffer (overlay on AsB0;
        // AsB0's last MFMA reader finished before the g=2 end-of-chunk barrier)
        #pragma unroll
        for (int mt = 0; mt < 4; ++mt)
            #pragma unroll
            for (int r = 0; r < 4; ++r) {
                float iv = sigmoidf_(acc[mt][0][r] + xga[mt][0][r]);
                float fv = sigmoidf_(acc[mt][1][r] + xga[mt][1][r]);
                float gv = tanhf_  (acc[mt][2][r] + xga[mt][2][r]);
                float ov = sigmoidf_(acc[mt][3][r] + xga[mt][3][r]);
                float cn = fv * cst[mt][r] + iv * gv;
                cst[mt][r] = cn;
                hlds[(64 * wm + 16 * mt + lq * 4 + r) * 32 + (wn * 16 + ln)] = f2bf(ov * tanhf_(cn));
            }
        __syncthreads();
        for (int c = tid; c < 512; c += 256) {
            const int row = c >> 2, seg = c & 3;
            intx4 d = *(const intx4*)(hlds + row * 32 + seg * 8);
            const unsigned short* p = hnext + (size_t)(arow0 + row) * 512 + j * 32 + seg * 8;
            asm volatile("global_store_dwordx4 %0, %1, off sc0 sc1" :: "v"(p), "v"(d) : "memory");
        }
        asm volatile("s_waitcnt vmcnt(0)" ::: "memory");
        __syncthreads();
        if (tid == 0) flag_post(flagp + j, tg + 1u);
        flag_prefetch(flagp, fpre);            // chunk-0 flags for t+1

        // projection of h_{t-1} (accumulated in the K-loop) -> out[:, t-1, :]
        if (jlt8) {
            #pragma unroll
            for (int r = 0; r < 4; ++r) {
                const int b = arow0 + j16 + lq * 4 + r;
                out[(size_t)b * (T_ * V_) + (t - 1) * V_ + v] = fmaxf(pacc[r] + fcb_v, 0.0f);
            }
        }
    }

    // ---- final projection of h_{T-1} ----
    if (jlt8) {
        wait4(flagp,      T_);   // vmcnt(0) inside also drains out-stores/prefetch
        wait4(flagp + 4,  T_);
        wait4(flagp + 8,  T_);
        wait4(flagp + 12, T_);
        const unsigned short* hlast = hb[(T_ - 1) & 1];
        floatx4 pa = zf;
        const int ar = arow0 + j16 + ln;
        #pragma unroll
        for (int kc = 0; kc < 16; ++kc) {
            const int k = kc * 32 + lq * 8;
            bf16x8 a = load16_sys(hlast + (size_t)ar * 512 + k);   // coherent read
            bf16x8 b = *(const bf16x8*)(fcw_bf + (size_t)v * 512 + k);
            pa = __builtin_amdgcn_mfma_f32_16x16x32_bf16(a, b, pa, 0, 0, 0);
        }
        #pragma unroll
        for (int r = 0; r < 4; ++r) {
            const int b = arow0 + j16 + lq * 4 + r;
            out[(size_t)b * (T_ * V_) + (T_ - 1) * V_ + v] = fmaxf(pa[r] + fcb_v, 0.0f);
        }
    }
}

// ---------------------------------------------------------------------------
extern "C" void kernel_launch(void* const* d_in, const int* in_sizes, int n_in,
                              void* d_out, int out_size, void* d_ws, size_t ws_size,
                              hipStream_t stream) {
    const float* z    = (const float*)d_in[0];
    const float* w_ih = (const float*)d_in[1];
    const float* w_hh = (const float*)d_in[2];
    const float* b_ih = (const float*)d_in[3];
    const float* b_hh = (const float*)d_in[4];
    const float* fc_w = (const float*)d_in[5];
    const float* fc_b = (const float*)d_in[6];
    float* out = (float*)d_out;

    char* ws = (char*)d_ws;
    size_t o = 0;
    auto take = [&](size_t bytes) { char* p = ws + o; o += (bytes + 255) & ~(size_t)255; return p; };
    unsigned short* Bp_hh  = (unsigned short*)take((size_t)FOURH * H_ * 2);
    unsigned short* Bp_ih  = (unsigned short*)take((size_t)FOURH * H_ * 2);
    unsigned short* z_bf   = (unsigned short*)take((size_t)B_ * H_ * 2);
    unsigned short* fcw_bf = (unsigned short*)take((size_t)V_ * H_ * 2);
    float*          biasp  = (float*)take((size_t)FOURH * 4);
    unsigned short* hbuf0  = (unsigned short*)take((size_t)B_ * H_ * 2);
    unsigned short* hbuf1  = (unsigned short*)take((size_t)B_ * H_ * 2);
    unsigned int*   cnt    = (unsigned int*)take(16 * 256);   // 16 groups x 64 uints
    float*          xg     = (float*)take((size_t)B_ * FOURH * 4);

    prep_kernel<<<(B_ * H_) / 256, 256, 0, stream>>>(z, w_ih, w_hh, b_ih, b_hh, fc_w,
                                                     Bp_ih, Bp_hh, z_bf, fcw_bf, biasp, cnt);
    xg_gemm_kernel<<<dim3(16, 16), 256, 0, stream>>>(z_bf, Bp_ih, biasp, xg);
    lstm_persistent<<<256, 256, 0, stream>>>(Bp_hh, fcw_bf, xg, fc_b,
                                             hbuf0, hbuf1, cnt, out);
}

// Round 5
// 1562.972 us; speedup vs baseline: 1.5381x; 1.5381x over previous
//
#include <hip/hip_runtime.h>
#include <hip/hip_bf16.h>
#include <cstdint>

#define B_   2048
#define H_   512
#define T_   128
#define V_   64
#define FOURH 2048

typedef __bf16 bf16x8 __attribute__((ext_vector_type(8)));
typedef float  floatx4 __attribute__((ext_vector_type(4)));
typedef int    intx4   __attribute__((ext_vector_type(4)));
typedef int    intx2   __attribute__((ext_vector_type(2)));

__device__ __forceinline__ unsigned short f2bf(float f) {
    union { float f; uint32_t u; } v; v.f = f;
    uint32_t r = v.u + 0x7fff + ((v.u >> 16) & 1);
    return (unsigned short)(r >> 16);
}

// v_rcp_f32 (~1 ulp, rel err ~1e-7 << bf16's 2^-8).
__device__ __forceinline__ float rcp_(float x) {
    float r; asm("v_rcp_f32 %0, %1" : "=v"(r) : "v"(x)); return r;
}
__device__ __forceinline__ float sigmoidf_(float x) {
    return rcp_(1.0f + __expf(-x));
}
__device__ __forceinline__ float tanhf_(float x) {
    float e = __expf(fminf(-2.0f * x, 80.0f));
    return (1.0f - e) * rcp_(1.0f + e);
}

__device__ __forceinline__ void global_to_lds16(const unsigned short* g, unsigned short* l) {
    __builtin_amdgcn_global_load_lds(
        (const __attribute__((address_space(1))) unsigned int*)g,
        (__attribute__((address_space(3))) unsigned int*)l, 16, 0, 0);
}

// System-coherent 16B load (bypass L1+L2, read MALL), blocking. R1-proven.
__device__ __forceinline__ bf16x8 load16_sys(const unsigned short* p) {
    bf16x8 d;
    asm volatile("global_load_dwordx4 %0, %1, off sc0 sc1\n\t"
                 "s_waitcnt vmcnt(0)"
                 : "=v"(d) : "v"(p));
    return d;
}

// ---------------------------------------------------------------------------
// Flag sync — R1-proven protocol, sc0 sc1 in BOTH directions, everywhere.
// (R3: sc0-only polls hang. R4: sc0-only data exchange reads stale/unwritten
// memory. Lesson recorded: only system-scope exchange is verified on gfx950.)
// Producer: h stores (sc0 sc1) -> vmcnt(0) -> flag store (sc0 sc1).
// Consumer: poll/prefetch flags with sc0 sc1 loads; data loads sc0 sc1.
// ---------------------------------------------------------------------------
__device__ __forceinline__ void flag_prefetch(const unsigned int* fp, intx4& f) {
    asm volatile("global_load_dwordx4 %0, %1, off sc0 sc1"
                 : "=v"(f) : "v"(fp) : "memory");
}
__device__ __forceinline__ bool flag_ok(const intx4& f, unsigned int tgt) {
    return (unsigned int)f[0] >= tgt && (unsigned int)f[1] >= tgt &&
           (unsigned int)f[2] >= tgt && (unsigned int)f[3] >= tgt;
}
__device__ __forceinline__ void wait4(const unsigned int* fp, unsigned int tgt) {
    for (;;) {
        intx4 f;
        asm volatile("global_load_dwordx4 %0, %1, off sc0 sc1\n\t"
                     "s_waitcnt vmcnt(0)" : "=v"(f) : "v"(fp) : "memory");
        if (flag_ok(f, tgt)) return;
        __builtin_amdgcn_s_sleep(1);
    }
}
__device__ __forceinline__ void flag_prefetch2(const unsigned int* fp, intx2& f) {
    asm volatile("global_load_dwordx2 %0, %1, off sc0 sc1"
                 : "=v"(f) : "v"(fp) : "memory");
}
__device__ __forceinline__ bool flag_ok2(const intx2& f, unsigned int tgt) {
    return (unsigned int)f[0] >= tgt && (unsigned int)f[1] >= tgt;
}
__device__ __forceinline__ void wait2(const unsigned int* fp, unsigned int tgt) {
    for (;;) {
        intx2 f;
        asm volatile("global_load_dwordx2 %0, %1, off sc0 sc1\n\t"
                     "s_waitcnt vmcnt(0)" : "=v"(f) : "v"(fp) : "memory");
        if (flag_ok2(f, tgt)) return;
        __builtin_amdgcn_s_sleep(1);
    }
}
__device__ __forceinline__ void flag_post(unsigned int* p, unsigned int v) {
    asm volatile("global_store_dword %0, %1, off sc0 sc1" :: "v"(p), "v"(v) : "memory");
}

// ---------------------------------------------------------------------------
// prep: permuted bf16 weights, bf16 z / fc_w, fused permuted bias, zero flags.
// Tile-col layout (per 128-col tile jt): c = 64*wnn + 16*gate + ln,
// maps to original gate row p = gate*512 + jt*32 + (wnn*16 + ln).
// ---------------------------------------------------------------------------
__global__ void prep_kernel(const float* __restrict__ z,
                            const float* __restrict__ w_ih,
                            const float* __restrict__ w_hh,
                            const float* __restrict__ b_ih,
                            const float* __restrict__ b_hh,
                            const float* __restrict__ fc_w,
                            unsigned short* __restrict__ Bp_ih,
                            unsigned short* __restrict__ Bp_hh,
                            unsigned short* __restrict__ z_bf,
                            unsigned short* __restrict__ fcw_bf,
                            float* __restrict__ biasp,
                            unsigned int* __restrict__ cnt) {
    int i = blockIdx.x * blockDim.x + threadIdx.x;   // 2048*512 threads
    int col = i >> 9, k = i & 511;
    int jj = col >> 7, cc = col & 127;
    int gate = (cc >> 4) & 3;
    int hcl = ((cc >> 6) << 4) | (cc & 15);
    int p = gate * 512 + jj * 32 + hcl;
    Bp_hh[i] = f2bf(w_hh[p * 512 + k]);
    Bp_ih[i] = f2bf(w_ih[p * 512 + k]);
    z_bf[i]  = f2bf(z[i]);
    if (i < V_ * H_) fcw_bf[i] = f2bf(fc_w[i]);
    if (i < FOURH) {
        int j2 = i >> 7, c2 = i & 127;
        int g2 = (c2 >> 4) & 3;
        int h2 = ((c2 >> 6) << 4) | (c2 & 15);
        int p2 = g2 * 512 + j2 * 32 + h2;
        biasp[i] = b_ih[p2] + b_hh[p2];
    }
    // 32 groups x 64 uints (256B stride): [0..7] h flags. Zero all.
    if (i < 2048) cnt[i] = 0;
}

// ---------------------------------------------------------------------------
// Round-1-proven 128x128 (K=512, BK=64) tile core for the x-gates GEMM.
// ---------------------------------------------------------------------------
__device__ __forceinline__ void gemm_tile_r1(
        const unsigned short* __restrict__ Aglob,
        const unsigned short* __restrict__ Bglob,
        int arow0, int brow0,
        unsigned short* As, unsigned short* Bs,
        floatx4 acc[2][8], int w, int l) {
    const int lr = l >> 3;
    const int gl = (l & 7) ^ lr;
    const int ln = l & 15, lq = l >> 4, ls = l & 7;
    for (int kc = 0; kc < 8; ++kc) {
        const int kof = kc * 64 + gl * 8;
        #pragma unroll
        for (int q = 0; q < 4; ++q) {
            const int r0 = (w * 4 + q) * 8;
            global_to_lds16(Aglob + (size_t)(arow0 + r0 + lr) * 512 + kof, As + r0 * 64);
            global_to_lds16(Bglob + (size_t)(brow0 + r0 + lr) * 512 + kof, Bs + r0 * 64);
        }
        __syncthreads();
        #pragma unroll
        for (int kk = 0; kk < 2; ++kk) {
            bf16x8 a[2], b[8];
            #pragma unroll
            for (int mt = 0; mt < 2; ++mt) {
                const int m = 32 * w + 16 * mt + ln;
                const int g = kk * 4 + lq;
                a[mt] = *(const bf16x8*)(As + m * 64 + ((g ^ ls) * 8));
            }
            #pragma unroll
            for (int nt = 0; nt < 8; ++nt) {
                const int n = 16 * nt + ln;
                const int g = kk * 4 + lq;
                b[nt] = *(const bf16x8*)(Bs + n * 64 + ((g ^ ls) * 8));
            }
            #pragma unroll
            for (int mt = 0; mt < 2; ++mt)
                #pragma unroll
                for (int nt = 0; nt < 8; ++nt)
                    acc[mt][nt] = __builtin_amdgcn_mfma_f32_16x16x32_bf16(
                        a[mt], b[nt], acc[mt][nt], 0, 0, 0);
        }
        __syncthreads();
    }
}

__global__ void __launch_bounds__(256) xg_gemm_kernel(
        const unsigned short* __restrict__ z_bf,
        const unsigned short* __restrict__ Bp_ih,
        const float* __restrict__ biasp,
        float* __restrict__ xg) {
    __shared__ unsigned short As[128 * 64];
    __shared__ unsigned short Bs[128 * 64];
    const int bi = blockIdx.x, j = blockIdx.y;
    const int tid = threadIdx.x, w = tid >> 6, l = tid & 63;
    floatx4 acc[2][8];
    const floatx4 zf = {0.f, 0.f, 0.f, 0.f};
    for (int a1 = 0; a1 < 2; ++a1) for (int a2 = 0; a2 < 8; ++a2) acc[a1][a2] = zf;

    gemm_tile_r1(z_bf, Bp_ih, bi * 128, j * 128, As, Bs, acc, w, l);

    const int ln = l & 15, lq = l >> 4;
    #pragma unroll
    for (int mt = 0; mt < 2; ++mt)
        #pragma unroll
        for (int nt = 0; nt < 8; ++nt) {
            const int colp = j * 128 + nt * 16 + ln;
            const float bv = biasp[colp];
            #pragma unroll
            for (int r = 0; r < 4; ++r) {
                const int b = bi * 128 + 32 * w + 16 * mt + lq * 4 + r;
                xg[(size_t)b * FOURH + colp] = acc[mt][nt][r] + bv;
            }
        }
}

// ---------------------------------------------------------------------------
// A staging, 64-row geometry: one kc sub-chunk (64 rows x 64 K-ushorts, 8KB)
// = 2 x 16B sc0/sc1 loads per thread, no wait.
// LDS sub-layout per kc (4096 ushorts): row r, slot s holds granule s^(r&7).
// ---------------------------------------------------------------------------
__device__ __forceinline__ void stage_issue2(const unsigned short* __restrict__ Aglob,
                                             int arow0, int kc, int w, int l,
                                             intx4& t0, intx4& t1) {
    const int lr = l >> 3;
    const int gl = (l & 7) ^ lr;
    const int kof = kc * 64 + gl * 8;
    const unsigned short* p0 = Aglob + (size_t)(arow0 + (w * 2 + 0) * 8 + lr) * 512 + kof;
    const unsigned short* p1 = Aglob + (size_t)(arow0 + (w * 2 + 1) * 8 + lr) * 512 + kof;
    asm volatile(
        "global_load_dwordx4 %0, %2, off sc0 sc1\n\t"
        "global_load_dwordx4 %1, %3, off sc0 sc1"
        : "=&v"(t0), "=&v"(t1)
        : "v"(p0), "v"(p1)
        : "memory");
}

// Commit a 16 KB chunk (2 kc sub-chunks, 4 regs) after a manual vmcnt wait.
__device__ __forceinline__ void commit4(unsigned short* buf, int w, int l,
                                        const intx4* u) {
    asm volatile("s_waitcnt vmcnt(0)" ::: "memory");
    const int lr = l >> 3, sl = (l & 7) * 8;
    #pragma unroll
    for (int kcL = 0; kcL < 2; ++kcL)
        #pragma unroll
        for (int q = 0; q < 2; ++q)
            *(intx4*)(buf + kcL * 4096 + ((w * 2 + q) * 8 + lr) * 64 + sl) = u[kcL * 2 + q];
}

// ---------------------------------------------------------------------------
// Persistent LSTM, 64-row x 256-col geometry: 32 groups x 8 WGs.
// WG bx: gi = bx&31 (group), j = bx>>5 (col-block 0..7). Group members share
// bx%8 -> XCD-local under round-robin (perf only; protocol is system-scope).
// Per WG: 64 batch rows x 256 gate cols; wave w owns all 64 rows x 64 cols
// (colbase = j*256 + (w>>1)*128 + (w&1)*64) -> per-wave shape identical to
// the proven R1 kernel (bq[16][4], acc[4][4], 256 MFMA/step).
// Per-step staging: 64 KB (half of R1) in 4 chunks x 16 KB, double-buffered,
// chunk g produced by WGs {2g, 2g+1} -> 2-flag waits. All h exchange and
// flags sc0 sc1 (the only verified-correct protocol on this part).
// ---------------------------------------------------------------------------
__global__ void __launch_bounds__(256, 1) lstm_persistent(
        const unsigned short* __restrict__ Bp_hh,
        const unsigned short* __restrict__ fcw_bf,
        const float* __restrict__ xg,
        const float* __restrict__ fc_b,
        unsigned short* __restrict__ h0b,
        unsigned short* __restrict__ h1b,
        unsigned int* __restrict__ cnt,
        float* __restrict__ out) {
    __shared__ unsigned short AsB0[8192];  // 16 KiB chunk buf 0 (first 8 KB doubles as hlds)
    __shared__ unsigned short AsB1[8192];  // 16 KiB chunk buf 1

    const int bx = blockIdx.x;
    const int gi = bx & 31;
    const int j  = bx >> 5;                // 0..7
    const int tid = threadIdx.x;
    const int w = tid >> 6, l = tid & 63;
    const int ln = l & 15, lq = l >> 4;
    const bool jlt4 = (j < 4);
    const int j16 = j * 16;
    const int v = 16 * w + ln;
    const float fcb_v = fc_b[v];
    const int arow0 = gi * 64;
    const int colbase = j * 256 + (w >> 1) * 128 + (w & 1) * 64;  // + 16*nt + ln
    unsigned int* flagp = cnt + gi * 64;   // 256B-padded per-group flag block
    const floatx4 zf = {0.f, 0.f, 0.f, 0.f};

    // ---- recurrent-weight fragments in registers (persistent) ----
    // bq[s][nt]: B row n = colbase + 16*nt + ln, k = 32*s + 8*lq .. +8
    bf16x8 bq[16][4];
    {
        const unsigned short* bbase =
            Bp_hh + ((size_t)(colbase + ln)) * 512 + lq * 8;
        #pragma unroll
        for (int s = 0; s < 16; ++s)
            #pragma unroll
            for (int nt = 0; nt < 4; ++nt)
                bq[s][nt] = *(const bf16x8*)(bbase + (size_t)nt * 16 * 512 + s * 32);
    }

    // ---- x-gate tile into registers ----
    floatx4 xga[4][4];
    #pragma unroll
    for (int mt = 0; mt < 4; ++mt)
        #pragma unroll
        for (int nt = 0; nt < 4; ++nt)
            #pragma unroll
            for (int r = 0; r < 4; ++r) {
                const int b = arow0 + 16 * mt + lq * 4 + r;
                xga[mt][nt][r] = xg[(size_t)b * FOURH + colbase + 16 * nt + ln];
            }

    // h transpose buffer: overlays AsB0 (dead at epilogue time)
    unsigned short* hlds = AsB0;           // 64 rows x 64 cols ushort = 8 KB

    // ---- t = 0: c0 = 0 -> c = i*g, h = o*tanh(c) ----
    // lane's h columns: hidden col = j*64 + 16*w + ln, rows 16*mt + lq*4 + r
    float cst[4][4];
    #pragma unroll
    for (int mt = 0; mt < 4; ++mt)
        #pragma unroll
        for (int r = 0; r < 4; ++r) {
            float iv = sigmoidf_(xga[mt][0][r]);
            float gv = tanhf_  (xga[mt][2][r]);
            float ov = sigmoidf_(xga[mt][3][r]);
            float cv = iv * gv;
            cst[mt][r] = cv;
            hlds[(16 * mt + lq * 4 + r) * 64 + (16 * w + ln)] = f2bf(ov * tanhf_(cv));
        }
    __syncthreads();
    for (int c = tid; c < 512; c += 256) {      // 64 rows x 4 segs... = 512 x 16B stores
        const int row = c >> 3, seg = c & 7;
        intx4 d = *(const intx4*)(hlds + row * 64 + seg * 8);
        const unsigned short* p = h0b + (size_t)(arow0 + row) * 512 + j * 64 + seg * 8;
        asm volatile("global_store_dwordx4 %0, %1, off sc0 sc1" :: "v"(p), "v"(d) : "memory");
    }
    asm volatile("s_waitcnt vmcnt(0)" ::: "memory");
    __syncthreads();
    if (tid == 0) flag_post(flagp + j, 1u);
    intx2 fpre2;
    flag_prefetch2(flagp, fpre2);              // chunk-0 flags (producers 0,1) for t=1

    unsigned short* hb[2] = {h0b, h1b};
    #pragma unroll 1
    for (int t = 1; t < T_; ++t) {
        const unsigned int tg = (unsigned int)t;

        // chunk-0 readiness: register fast path, poll fallback
        asm volatile("s_waitcnt vmcnt(0)" ::: "memory");
        __builtin_amdgcn_sched_barrier(0);
        if (!flag_ok2(fpre2, tg)) wait2(flagp, tg);

        const unsigned short* hprev = hb[(t - 1) & 1];
        unsigned short* hnext = hb[t & 1];

        floatx4 acc[4][4];
        #pragma unroll
        for (int a1 = 0; a1 < 4; ++a1)
            #pragma unroll
            for (int a2 = 0; a2 < 4; ++a2) acc[a1][a2] = zf;
        floatx4 pacc = zf;

        // ---- chunk 0 (kc 0,1): only exposed staging latency of the step ----
        intx4 u[4];
        stage_issue2(hprev, arow0, 0, w, l, u[0], u[1]);
        stage_issue2(hprev, arow0, 1, w, l, u[2], u[3]);
        flag_prefetch2(flagp + 2, fpre2);      // chunk-1 producers (drained by commit4)
        commit4(AsB0, w, l, u);
        __syncthreads();

        #pragma unroll
        for (int g = 0; g < 4; ++g) {
            if (g < 3) {   // loads for chunk g+1 fly across this chunk's MFMA
                __builtin_amdgcn_sched_barrier(0);
                if (!flag_ok2(fpre2, tg)) wait2(flagp + 2 * (g + 1), tg);
                stage_issue2(hprev, arow0, 2 * g + 2, w, l, u[0], u[1]);
                stage_issue2(hprev, arow0, 2 * g + 3, w, l, u[2], u[3]);
                if (g < 2) flag_prefetch2(flagp + 2 * (g + 2), fpre2);
            }
            const unsigned short* buf = (g & 1) ? AsB1 : AsB0;
            #pragma unroll
            for (int ss = 0; ss < 4; ++ss) {
                const int s = g * 4 + ss;
                const int ga = (ss & 1) * 4 + lq;
                const unsigned short* Ac = buf + (ss >> 1) * 4096;
                bf16x8 af[4];
                #pragma unroll
                for (int mt = 0; mt < 4; ++mt) {
                    const int m = 16 * mt + ln;
                    af[mt] = *(const bf16x8*)(Ac + m * 64 + ((ga ^ (ln & 7)) * 8));
                }
                #pragma unroll
                for (int mt = 0; mt < 4; ++mt)
                    #pragma unroll
                    for (int nt = 0; nt < 4; ++nt)
                        acc[mt][nt] = __builtin_amdgcn_mfma_f32_16x16x32_bf16(
                            af[mt], bq[s][nt], acc[mt][nt], 0, 0, 0);
                if (jlt4) {
                    bf16x8 ap = *(const bf16x8*)(Ac + (j16 + ln) * 64 + ((ga ^ (ln & 7)) * 8));
                    bf16x8 bp = *(const bf16x8*)(fcw_bf + (size_t)v * 512 + s * 32 + lq * 8);
                    pacc = __builtin_amdgcn_mfma_f32_16x16x32_bf16(ap, bp, pacc, 0, 0, 0);
                }
            }
            if (g < 3) {
                commit4((g & 1) ? AsB0 : AsB1, w, l, u);
                __syncthreads();
            }
        }

        // cell update -> h values into LDS transpose buffer (overlay on AsB0;
        // AsB0's last MFMA reader finished before the g=2 end-of-chunk barrier)
        #pragma unroll
        for (int mt = 0; mt < 4; ++mt)
            #pragma unroll
            for (int r = 0; r < 4; ++r) {
                float iv = sigmoidf_(acc[mt][0][r] + xga[mt][0][r]);
                float fv = sigmoidf_(acc[mt][1][r] + xga[mt][1][r]);
                float gv = tanhf_  (acc[mt][2][r] + xga[mt][2][r]);
                float ov = sigmoidf_(acc[mt][3][r] + xga[mt][3][r]);
                float cn = fv * cst[mt][r] + iv * gv;
                cst[mt][r] = cn;
                hlds[(16 * mt + lq * 4 + r) * 64 + (16 * w + ln)] = f2bf(ov * tanhf_(cn));
            }
        __syncthreads();
        for (int c = tid; c < 512; c += 256) {
            const int row = c >> 3, seg = c & 7;
            intx4 d = *(const intx4*)(hlds + row * 64 + seg * 8);
            const unsigned short* p = hnext + (size_t)(arow0 + row) * 512 + j * 64 + seg * 8;
            asm volatile("global_store_dwordx4 %0, %1, off sc0 sc1" :: "v"(p), "v"(d) : "memory");
        }
        asm volatile("s_waitcnt vmcnt(0)" ::: "memory");
        __syncthreads();
        if (tid == 0) flag_post(flagp + j, tg + 1u);
        flag_prefetch2(flagp, fpre2);          // chunk-0 flags for t+1

        // projection of h_{t-1} (accumulated in the K-loop) -> out[:, t-1, :]
        if (jlt4) {
            #pragma unroll
            for (int r = 0; r < 4; ++r) {
                const int b = arow0 + j16 + lq * 4 + r;
                out[(size_t)b * (T_ * V_) + (t - 1) * V_ + v] = fmaxf(pacc[r] + fcb_v, 0.0f);
            }
        }
    }

    // ---- final projection of h_{T-1} ----
    if (jlt4) {
        wait4(flagp,     T_);   // vmcnt(0) inside also drains out-stores/prefetch
        wait4(flagp + 4, T_);
        const unsigned short* hlast = hb[(T_ - 1) & 1];
        floatx4 pa = zf;
        const int ar = arow0 + j16 + ln;
        #pragma unroll
        for (int kc = 0; kc < 16; ++kc) {
            const int k = kc * 32 + lq * 8;
            bf16x8 a = load16_sys(hlast + (size_t)ar * 512 + k);   // coherent read
            bf16x8 b = *(const bf16x8*)(fcw_bf + (size_t)v * 512 + k);
            pa = __builtin_amdgcn_mfma_f32_16x16x32_bf16(a, b, pa, 0, 0, 0);
        }
        #pragma unroll
        for (int r = 0; r < 4; ++r) {
            const int b = arow0 + j16 + lq * 4 + r;
            out[(size_t)b * (T_ * V_) + (T_ - 1) * V_ + v] = fmaxf(pa[r] + fcb_v, 0.0f);
        }
    }
}

// ---------------------------------------------------------------------------
extern "C" void kernel_launch(void* const* d_in, const int* in_sizes, int n_in,
                              void* d_out, int out_size, void* d_ws, size_t ws_size,
                              hipStream_t stream) {
    const float* z    = (const float*)d_in[0];
    const float* w_ih = (const float*)d_in[1];
    const float* w_hh = (const float*)d_in[2];
    const float* b_ih = (const float*)d_in[3];
    const float* b_hh = (const float*)d_in[4];
    const float* fc_w = (const float*)d_in[5];
    const float* fc_b = (const float*)d_in[6];
    float* out = (float*)d_out;

    char* ws = (char*)d_ws;
    size_t o = 0;
    auto take = [&](size_t bytes) { char* p = ws + o; o += (bytes + 255) & ~(size_t)255; return p; };
    unsigned short* Bp_hh  = (unsigned short*)take((size_t)FOURH * H_ * 2);
    unsigned short* Bp_ih  = (unsigned short*)take((size_t)FOURH * H_ * 2);
    unsigned short* z_bf   = (unsigned short*)take((size_t)B_ * H_ * 2);
    unsigned short* fcw_bf = (unsigned short*)take((size_t)V_ * H_ * 2);
    float*          biasp  = (float*)take((size_t)FOURH * 4);
    unsigned short* hbuf0  = (unsigned short*)take((size_t)B_ * H_ * 2);
    unsigned short* hbuf1  = (unsigned short*)take((size_t)B_ * H_ * 2);
    unsigned int*   cnt    = (unsigned int*)take(32 * 256);   // 32 groups x 64 uints
    float*          xg     = (float*)take((size_t)B_ * FOURH * 4);

    prep_kernel<<<(B_ * H_) / 256, 256, 0, stream>>>(z, w_ih, w_hh, b_ih, b_hh, fc_w,
                                                     Bp_ih, Bp_hh, z_bf, fcw_bf, biasp, cnt);
    xg_gemm_kernel<<<dim3(16, 16), 256, 0, stream>>>(z_bf, Bp_ih, biasp, xg);
    lstm_persistent<<<256, 256, 0, stream>>>(Bp_hh, fcw_bf, xg, fc_b,
                                             hbuf0, hbuf1, cnt, out);
}

// Round 6
// 1525.377 us; speedup vs baseline: 1.5760x; 1.0246x over previous
//
#include <hip/hip_runtime.h>
#include <hip/hip_bf16.h>
#include <cstdint>

#define B_   2048
#define H_   512
#define T_   128
#define V_   64
#define FOURH 2048

typedef __bf16 bf16x8 __attribute__((ext_vector_type(8)));
typedef float  floatx4 __attribute__((ext_vector_type(4)));
typedef int    intx4   __attribute__((ext_vector_type(4)));

__device__ __forceinline__ unsigned short f2bf(float f) {
    union { float f; uint32_t u; } v; v.f = f;
    uint32_t r = v.u + 0x7fff + ((v.u >> 16) & 1);
    return (unsigned short)(r >> 16);
}

// v_rcp_f32 (~1 ulp, rel err ~1e-7 << bf16's 2^-8).
__device__ __forceinline__ float rcp_(float x) {
    float r; asm("v_rcp_f32 %0, %1" : "=v"(r) : "v"(x)); return r;
}
__device__ __forceinline__ float sigmoidf_(float x) {
    return rcp_(1.0f + __expf(-x));
}
__device__ __forceinline__ float tanhf_(float x) {
    float e = __expf(fminf(-2.0f * x, 80.0f));
    return (1.0f - e) * rcp_(1.0f + e);
}

__device__ __forceinline__ void global_to_lds16(const unsigned short* g, unsigned short* l) {
    __builtin_amdgcn_global_load_lds(
        (const __attribute__((address_space(1))) unsigned int*)g,
        (__attribute__((address_space(3))) unsigned int*)l, 16, 0, 0);
}

// System-coherent 16B load (bypass L1+L2, read MALL), blocking. R1-proven.
__device__ __forceinline__ bf16x8 load16_sys(const unsigned short* p) {
    bf16x8 d;
    asm volatile("global_load_dwordx4 %0, %1, off sc0 sc1\n\t"
                 "s_waitcnt vmcnt(0)"
                 : "=v"(d) : "v"(p));
    return d;
}

// ---------------------------------------------------------------------------
// Flag sync — R1-proven protocol, sc0 sc1 in BOTH directions, everywhere.
// Producer: h stores (sc0 sc1) -> vmcnt(0) -> flag store (sc0 sc1).
// Consumer: poll/prefetch flags with sc0 sc1 loads; data loads sc0 sc1.
// ---------------------------------------------------------------------------
__device__ __forceinline__ void flag_prefetch(const unsigned int* fp, intx4& f) {
    asm volatile("global_load_dwordx4 %0, %1, off sc0 sc1"
                 : "=v"(f) : "v"(fp) : "memory");
}
__device__ __forceinline__ bool flag_ok(const intx4& f, unsigned int tgt) {
    return (unsigned int)f[0] >= tgt && (unsigned int)f[1] >= tgt &&
           (unsigned int)f[2] >= tgt && (unsigned int)f[3] >= tgt;
}
__device__ __forceinline__ void wait4(const unsigned int* fp, unsigned int tgt) {
    for (;;) {
        intx4 f;
        asm volatile("global_load_dwordx4 %0, %1, off sc0 sc1\n\t"
                     "s_waitcnt vmcnt(0)" : "=v"(f) : "v"(fp) : "memory");
        if (flag_ok(f, tgt)) return;
        __builtin_amdgcn_s_sleep(1);
    }
}
__device__ __forceinline__ void flag_post(unsigned int* p, unsigned int v) {
    asm volatile("global_store_dword %0, %1, off sc0 sc1" :: "v"(p), "v"(v) : "memory");
}

// ---------------------------------------------------------------------------
// prep: permuted bf16 weights, bf16 z / fc_w, fused permuted bias, zero flags.
// ---------------------------------------------------------------------------
__global__ void prep_kernel(const float* __restrict__ z,
                            const float* __restrict__ w_ih,
                            const float* __restrict__ w_hh,
                            const float* __restrict__ b_ih,
                            const float* __restrict__ b_hh,
                            const float* __restrict__ fc_w,
                            unsigned short* __restrict__ Bp_ih,
                            unsigned short* __restrict__ Bp_hh,
                            unsigned short* __restrict__ z_bf,
                            unsigned short* __restrict__ fcw_bf,
                            float* __restrict__ biasp,
                            unsigned int* __restrict__ cnt) {
    int i = blockIdx.x * blockDim.x + threadIdx.x;   // 2048*512 threads
    int col = i >> 9, k = i & 511;
    int jj = col >> 7, cc = col & 127;
    int gate = (cc >> 4) & 3;
    int hcl = ((cc >> 6) << 4) | (cc & 15);
    int p = gate * 512 + jj * 32 + hcl;
    Bp_hh[i] = f2bf(w_hh[p * 512 + k]);
    Bp_ih[i] = f2bf(w_ih[p * 512 + k]);
    z_bf[i]  = f2bf(z[i]);
    if (i < V_ * H_) fcw_bf[i] = f2bf(fc_w[i]);
    if (i < FOURH) {
        int j2 = i >> 7, c2 = i & 127;
        int g2 = (c2 >> 4) & 3;
        int h2 = ((c2 >> 6) << 4) | (c2 & 15);
        int p2 = g2 * 512 + j2 * 32 + h2;
        biasp[i] = b_ih[p2] + b_hh[p2];
    }
    // 32 groups x 64 uints (256B stride): [0..7] h flags. Zero all.
    if (i < 2048) cnt[i] = 0;
}

// ---------------------------------------------------------------------------
// Round-1-proven 128x128 (K=512, BK=64) tile core for the x-gates GEMM.
// ---------------------------------------------------------------------------
__device__ __forceinline__ void gemm_tile_r1(
        const unsigned short* __restrict__ Aglob,
        const unsigned short* __restrict__ Bglob,
        int arow0, int brow0,
        unsigned short* As, unsigned short* Bs,
        floatx4 acc[2][8], int w, int l) {
    const int lr = l >> 3;
    const int gl = (l & 7) ^ lr;
    const int ln = l & 15, lq = l >> 4, ls = l & 7;
    for (int kc = 0; kc < 8; ++kc) {
        const int kof = kc * 64 + gl * 8;
        #pragma unroll
        for (int q = 0; q < 4; ++q) {
            const int r0 = (w * 4 + q) * 8;
            global_to_lds16(Aglob + (size_t)(arow0 + r0 + lr) * 512 + kof, As + r0 * 64);
            global_to_lds16(Bglob + (size_t)(brow0 + r0 + lr) * 512 + kof, Bs + r0 * 64);
        }
        __syncthreads();
        #pragma unroll
        for (int kk = 0; kk < 2; ++kk) {
            bf16x8 a[2], b[8];
            #pragma unroll
            for (int mt = 0; mt < 2; ++mt) {
                const int m = 32 * w + 16 * mt + ln;
                const int g = kk * 4 + lq;
                a[mt] = *(const bf16x8*)(As + m * 64 + ((g ^ ls) * 8));
            }
            #pragma unroll
            for (int nt = 0; nt < 8; ++nt) {
                const int n = 16 * nt + ln;
                const int g = kk * 4 + lq;
                b[nt] = *(const bf16x8*)(Bs + n * 64 + ((g ^ ls) * 8));
            }
            #pragma unroll
            for (int mt = 0; mt < 2; ++mt)
                #pragma unroll
                for (int nt = 0; nt < 8; ++nt)
                    acc[mt][nt] = __builtin_amdgcn_mfma_f32_16x16x32_bf16(
                        a[mt], b[nt], acc[mt][nt], 0, 0, 0);
        }
        __syncthreads();
    }
}

__global__ void __launch_bounds__(256) xg_gemm_kernel(
        const unsigned short* __restrict__ z_bf,
        const unsigned short* __restrict__ Bp_ih,
        const float* __restrict__ biasp,
        float* __restrict__ xg) {
    __shared__ unsigned short As[128 * 64];
    __shared__ unsigned short Bs[128 * 64];
    const int bi = blockIdx.x, j = blockIdx.y;
    const int tid = threadIdx.x, w = tid >> 6, l = tid & 63;
    floatx4 acc[2][8];
    const floatx4 zf = {0.f, 0.f, 0.f, 0.f};
    for (int a1 = 0; a1 < 2; ++a1) for (int a2 = 0; a2 < 8; ++a2) acc[a1][a2] = zf;

    gemm_tile_r1(z_bf, Bp_ih, bi * 128, j * 128, As, Bs, acc, w, l);

    const int ln = l & 15, lq = l >> 4;
    #pragma unroll
    for (int mt = 0; mt < 2; ++mt)
        #pragma unroll
        for (int nt = 0; nt < 8; ++nt) {
            const int colp = j * 128 + nt * 16 + ln;
            const float bv = biasp[colp];
            #pragma unroll
            for (int r = 0; r < 4; ++r) {
                const int b = bi * 128 + 32 * w + 16 * mt + lq * 4 + r;
                xg[(size_t)b * FOURH + colp] = acc[mt][nt][r] + bv;
            }
        }
}

// ---------------------------------------------------------------------------
// A staging, 64-row geometry: one kc sub-chunk (64 rows x 64 K-ushorts, 8KB)
// = 2 x 16B sc0/sc1 loads per thread, no wait.
// LDS sub-layout per kc (4096 ushorts): row r, slot s holds granule s^(r&7).
// ---------------------------------------------------------------------------
__device__ __forceinline__ void stage_issue2(const unsigned short* __restrict__ Aglob,
                                             int arow0, int kc, int w, int l,
                                             intx4& t0, intx4& t1) {
    const int lr = l >> 3;
    const int gl = (l & 7) ^ lr;
    const int kof = kc * 64 + gl * 8;
    const unsigned short* p0 = Aglob + (size_t)(arow0 + (w * 2 + 0) * 8 + lr) * 512 + kof;
    const unsigned short* p1 = Aglob + (size_t)(arow0 + (w * 2 + 1) * 8 + lr) * 512 + kof;
    asm volatile(
        "global_load_dwordx4 %0, %2, off sc0 sc1\n\t"
        "global_load_dwordx4 %1, %3, off sc0 sc1"
        : "=&v"(t0), "=&v"(t1)
        : "v"(p0), "v"(p1)
        : "memory");
}

// Commit a 16 KB chunk (2 kc sub-chunks, 4 regs) after a COUNTED vmcnt wait.
// N = number of younger staging loads allowed to remain in flight; with all
// 16 step loads issued up-front, chunk g commits with N = 12-4g, so chunks
// g+1..3 keep flying across chunk g's MFMA block (deep pipeline).
template<int N>
__device__ __forceinline__ void commit4c(unsigned short* buf, int w, int l,
                                         const intx4* u) {
    if constexpr (N == 12) asm volatile("s_waitcnt vmcnt(12)" ::: "memory");
    else if constexpr (N == 8)  asm volatile("s_waitcnt vmcnt(8)"  ::: "memory");
    else if constexpr (N == 4)  asm volatile("s_waitcnt vmcnt(4)"  ::: "memory");
    else                        asm volatile("s_waitcnt vmcnt(0)"  ::: "memory");
    const int lr = l >> 3, sl = (l & 7) * 8;
    #pragma unroll
    for (int kcL = 0; kcL < 2; ++kcL)
        #pragma unroll
        for (int q = 0; q < 2; ++q)
            *(intx4*)(buf + kcL * 4096 + ((w * 2 + q) * 8 + lr) * 64 + sl) = u[kcL * 2 + q];
}

// ---------------------------------------------------------------------------
// Persistent LSTM, 64-row x 256-col geometry: 32 groups x 8 WGs.
// Deep-pipelined step: wait ALL 8 producer flags once, then issue ALL 64 KB
// of staging loads up-front (16 VM ops/wave), commit chunks with counted
// vmcnt(12/8/4/0). Exposed MALL latency per step collapses from ~4 round
// trips (1-chunk lookahead) to ~1 (chunk-0 only); chunks 1-3 land under
// chunk 0's RT + the MFMA stream. vmcnt counts are exact because the
// top-of-step vmcnt(0) (which drains the flag prefetch + out stores) zeroes
// outstanding VM ops before the 16 loads are issued.
// All h exchange and flags sc0 sc1 (the only verified-correct protocol).
// ---------------------------------------------------------------------------
__global__ void __launch_bounds__(256, 1) lstm_persistent(
        const unsigned short* __restrict__ Bp_hh,
        const unsigned short* __restrict__ fcw_bf,
        const float* __restrict__ xg,
        const float* __restrict__ fc_b,
        unsigned short* __restrict__ h0b,
        unsigned short* __restrict__ h1b,
        unsigned int* __restrict__ cnt,
        float* __restrict__ out) {
    __shared__ unsigned short AsB0[4096 * 2];  // 16 KiB chunk buf 0 (first 8 KB doubles as hlds)
    __shared__ unsigned short AsB1[4096 * 2];  // 16 KiB chunk buf 1

    const int bx = blockIdx.x;
    const int gi = bx & 31;
    const int j  = bx >> 5;                // 0..7
    const int tid = threadIdx.x;
    const int w = tid >> 6, l = tid & 63;
    const int ln = l & 15, lq = l >> 4;
    const bool jlt4 = (j < 4);
    const int j16 = j * 16;
    const int v = 16 * w + ln;
    const float fcb_v = fc_b[v];
    const int arow0 = gi * 64;
    const int colbase = j * 256 + (w >> 1) * 128 + (w & 1) * 64;  // + 16*nt + ln
    unsigned int* flagp = cnt + gi * 64;   // 256B-padded per-group flag block
    const floatx4 zf = {0.f, 0.f, 0.f, 0.f};

    // ---- recurrent-weight fragments in registers (persistent) ----
    bf16x8 bq[16][4];
    {
        const unsigned short* bbase =
            Bp_hh + ((size_t)(colbase + ln)) * 512 + lq * 8;
        #pragma unroll
        for (int s = 0; s < 16; ++s)
            #pragma unroll
            for (int nt = 0; nt < 4; ++nt)
                bq[s][nt] = *(const bf16x8*)(bbase + (size_t)nt * 16 * 512 + s * 32);
    }

    // ---- x-gate tile into registers ----
    floatx4 xga[4][4];
    #pragma unroll
    for (int mt = 0; mt < 4; ++mt)
        #pragma unroll
        for (int nt = 0; nt < 4; ++nt)
            #pragma unroll
            for (int r = 0; r < 4; ++r) {
                const int b = arow0 + 16 * mt + lq * 4 + r;
                xga[mt][nt][r] = xg[(size_t)b * FOURH + colbase + 16 * nt + ln];
            }

    // h transpose buffer: overlays AsB0 (dead at epilogue time)
    unsigned short* hlds = AsB0;           // 64 rows x 64 cols ushort = 8 KB

    // ---- t = 0: c0 = 0 -> c = i*g, h = o*tanh(c) ----
    float cst[4][4];
    #pragma unroll
    for (int mt = 0; mt < 4; ++mt)
        #pragma unroll
        for (int r = 0; r < 4; ++r) {
            float iv = sigmoidf_(xga[mt][0][r]);
            float gv = tanhf_  (xga[mt][2][r]);
            float ov = sigmoidf_(xga[mt][3][r]);
            float cv = iv * gv;
            cst[mt][r] = cv;
            hlds[(16 * mt + lq * 4 + r) * 64 + (16 * w + ln)] = f2bf(ov * tanhf_(cv));
        }
    __syncthreads();
    for (int c = tid; c < 512; c += 256) {
        const int row = c >> 3, seg = c & 7;
        intx4 d = *(const intx4*)(hlds + row * 64 + seg * 8);
        const unsigned short* p = h0b + (size_t)(arow0 + row) * 512 + j * 64 + seg * 8;
        asm volatile("global_store_dwordx4 %0, %1, off sc0 sc1" :: "v"(p), "v"(d) : "memory");
    }
    asm volatile("s_waitcnt vmcnt(0)" ::: "memory");
    __syncthreads();
    if (tid == 0) flag_post(flagp + j, 1u);
    intx4 fpreA, fpreB;
    flag_prefetch(flagp,     fpreA);       // all 8 producer flags for t=1
    flag_prefetch(flagp + 4, fpreB);

    unsigned short* hb[2] = {h0b, h1b};
    #pragma unroll 1
    for (int t = 1; t < T_; ++t) {
        const unsigned int tg = (unsigned int)t;

        // step readiness: single wait for ALL 8 producers (register fast path)
        asm volatile("s_waitcnt vmcnt(0)" ::: "memory");
        __builtin_amdgcn_sched_barrier(0);
        if (!(flag_ok(fpreA, tg) && flag_ok(fpreB, tg))) {
            wait4(flagp, tg);
            wait4(flagp + 4, tg);
        }

        const unsigned short* hprev = hb[(t - 1) & 1];
        unsigned short* hnext = hb[t & 1];

        floatx4 acc[4][4];
        #pragma unroll
        for (int a1 = 0; a1 < 4; ++a1)
            #pragma unroll
            for (int a2 = 0; a2 < 4; ++a2) acc[a1][a2] = zf;
        floatx4 pacc = zf;

        // ---- issue ALL 16 staging loads up-front (64 KB, 4 chunks) ----
        intx4 u[16];
        #pragma unroll
        for (int g = 0; g < 4; ++g) {
            stage_issue2(hprev, arow0, 2 * g,     w, l, u[4 * g + 0], u[4 * g + 1]);
            stage_issue2(hprev, arow0, 2 * g + 1, w, l, u[4 * g + 2], u[4 * g + 3]);
        }
        commit4c<12>(AsB0, w, l, &u[0]);   // chunk 0: wait only its 4 loads
        __syncthreads();

        #pragma unroll
        for (int g = 0; g < 4; ++g) {
            const unsigned short* buf = (g & 1) ? AsB1 : AsB0;
            #pragma unroll
            for (int ss = 0; ss < 4; ++ss) {
                const int s = g * 4 + ss;
                const int ga = (ss & 1) * 4 + lq;
                const unsigned short* Ac = buf + (ss >> 1) * 4096;
                bf16x8 af[4];
                #pragma unroll
                for (int mt = 0; mt < 4; ++mt) {
                    const int m = 16 * mt + ln;
                    af[mt] = *(const bf16x8*)(Ac + m * 64 + ((ga ^ (ln & 7)) * 8));
                }
                #pragma unroll
                for (int mt = 0; mt < 4; ++mt)
                    #pragma unroll
                    for (int nt = 0; nt < 4; ++nt)
                        acc[mt][nt] = __builtin_amdgcn_mfma_f32_16x16x32_bf16(
                            af[mt], bq[s][nt], acc[mt][nt], 0, 0, 0);
                if (jlt4) {
                    bf16x8 ap = *(const bf16x8*)(Ac + (j16 + ln) * 64 + ((ga ^ (ln & 7)) * 8));
                    bf16x8 bp = *(const bf16x8*)(fcw_bf + (size_t)v * 512 + s * 32 + lq * 8);
                    pacc = __builtin_amdgcn_mfma_f32_16x16x32_bf16(ap, bp, pacc, 0, 0, 0);
                }
            }
            if (g == 0) { commit4c<8>(AsB1, w, l, &u[4]);  __syncthreads(); }
            else if (g == 1) { commit4c<4>(AsB0, w, l, &u[8]);  __syncthreads(); }
            else if (g == 2) { commit4c<0>(AsB1, w, l, &u[12]); __syncthreads(); }
        }

        // cell update -> h values into LDS transpose buffer (overlay on AsB0;
        // last AsB0 reader was chunk-2 MFMA, fenced by the g==2 barrier)
        #pragma unroll
        for (int mt = 0; mt < 4; ++mt)
            #pragma unroll
            for (int r = 0; r < 4; ++r) {
                float iv = sigmoidf_(acc[mt][0][r] + xga[mt][0][r]);
                float fv = sigmoidf_(acc[mt][1][r] + xga[mt][1][r]);
                float gv = tanhf_  (acc[mt][2][r] + xga[mt][2][r]);
                float ov = sigmoidf_(acc[mt][3][r] + xga[mt][3][r]);
                float cn = fv * cst[mt][r] + iv * gv;
                cst[mt][r] = cn;
                hlds[(16 * mt + lq * 4 + r) * 64 + (16 * w + ln)] = f2bf(ov * tanhf_(cn));
            }
        __syncthreads();
        for (int c = tid; c < 512; c += 256) {
            const int row = c >> 3, seg = c & 7;
            intx4 d = *(const intx4*)(hlds + row * 64 + seg * 8);
            const unsigned short* p = hnext + (size_t)(arow0 + row) * 512 + j * 64 + seg * 8;
            asm volatile("global_store_dwordx4 %0, %1, off sc0 sc1" :: "v"(p), "v"(d) : "memory");
        }
        asm volatile("s_waitcnt vmcnt(0)" ::: "memory");
        __syncthreads();
        if (tid == 0) flag_post(flagp + j, tg + 1u);
        flag_prefetch(flagp,     fpreA);   // all 8 flags for t+1
        flag_prefetch(flagp + 4, fpreB);

        // projection of h_{t-1} (accumulated in the K-loop) -> out[:, t-1, :]
        // issued after the flag post; drained by next step's top vmcnt(0)
        if (jlt4) {
            #pragma unroll
            for (int r = 0; r < 4; ++r) {
                const int b = arow0 + j16 + lq * 4 + r;
                out[(size_t)b * (T_ * V_) + (t - 1) * V_ + v] = fmaxf(pacc[r] + fcb_v, 0.0f);
            }
        }
    }

    // ---- final projection of h_{T-1} ----
    if (jlt4) {
        wait4(flagp,     T_);   // vmcnt(0) inside also drains out-stores/prefetch
        wait4(flagp + 4, T_);
        const unsigned short* hlast = hb[(T_ - 1) & 1];
        floatx4 pa = zf;
        const int ar = arow0 + j16 + ln;
        #pragma unroll
        for (int kc = 0; kc < 16; ++kc) {
            const int k = kc * 32 + lq * 8;
            bf16x8 a = load16_sys(hlast + (size_t)ar * 512 + k);   // coherent read
            bf16x8 b = *(const bf16x8*)(fcw_bf + (size_t)v * 512 + k);
            pa = __builtin_amdgcn_mfma_f32_16x16x32_bf16(a, b, pa, 0, 0, 0);
        }
        #pragma unroll
        for (int r = 0; r < 4; ++r) {
            const int b = arow0 + j16 + lq * 4 + r;
            out[(size_t)b * (T_ * V_) + (T_ - 1) * V_ + v] = fmaxf(pa[r] + fcb_v, 0.0f);
        }
    }
}

// ---------------------------------------------------------------------------
extern "C" void kernel_launch(void* const* d_in, const int* in_sizes, int n_in,
                              void* d_out, int out_size, void* d_ws, size_t ws_size,
                              hipStream_t stream) {
    const float* z    = (const float*)d_in[0];
    const float* w_ih = (const float*)d_in[1];
    const float* w_hh = (const float*)d_in[2];
    const float* b_ih = (const float*)d_in[3];
    const float* b_hh = (const float*)d_in[4];
    const float* fc_w = (const float*)d_in[5];
    const float* fc_b = (const float*)d_in[6];
    float* out = (float*)d_out;

    char* ws = (char*)d_ws;
    size_t o = 0;
    auto take = [&](size_t bytes) { char* p = ws + o; o += (bytes + 255) & ~(size_t)255; return p; };
    unsigned short* Bp_hh  = (unsigned short*)take((size_t)FOURH * H_ * 2);
    unsigned short* Bp_ih  = (unsigned short*)take((size_t)FOURH * H_ * 2);
    unsigned short* z_bf   = (unsigned short*)take((size_t)B_ * H_ * 2);
    unsigned short* fcw_bf = (unsigned short*)take((size_t)V_ * H_ * 2);
    float*          biasp  = (float*)take((size_t)FOURH * 4);
    unsigned short* hbuf0  = (unsigned short*)take((size_t)B_ * H_ * 2);
    unsigned short* hbuf1  = (unsigned short*)take((size_t)B_ * H_ * 2);
    unsigned int*   cnt    = (unsigned int*)take(32 * 256);   // 32 groups x 64 uints
    float*          xg     = (float*)take((size_t)B_ * FOURH * 4);

    prep_kernel<<<(B_ * H_) / 256, 256, 0, stream>>>(z, w_ih, w_hh, b_ih, b_hh, fc_w,
                                                     Bp_ih, Bp_hh, z_bf, fcw_bf, biasp, cnt);
    xg_gemm_kernel<<<dim3(16, 16), 256, 0, stream>>>(z_bf, Bp_ih, biasp, xg);
    lstm_persistent<<<256, 256, 0, stream>>>(Bp_hh, fcw_bf, xg, fc_b,
                                             hbuf0, hbuf1, cnt, out);
}